// Round 3
// baseline (150.110 us; speedup 1.0000x reference)
//
#include <hip/hip_runtime.h>

#define B_ 16
#define T_ 4096
#define D_ 128
#define L_ 128
#define NC_ 32            // T_/L_
#define CH_ (B_*NC_)      // 512 chunks
#define LDK 136           // padded bf16 row stride (272B, 16B-aligned rows)

typedef __attribute__((ext_vector_type(8))) short bf16x8;
typedef __attribute__((ext_vector_type(4))) float f32x4;

__device__ __forceinline__ float clampf(float x, float lo, float hi) {
    return fminf(fmaxf(x, lo), hi);
}
__device__ __forceinline__ float phi_f(float x) {   // elu(x)+1
    return x > 0.f ? x + 1.f : expf(x);
}
__device__ __forceinline__ float4 phi4(float4 a) {
    float4 r; r.x = phi_f(a.x); r.y = phi_f(a.y); r.z = phi_f(a.z); r.w = phi_f(a.w); return r;
}
__device__ __forceinline__ unsigned short bf16r(float f) {  // RNE f32->bf16
    unsigned u = __builtin_bit_cast(unsigned, f);
    u += 0x7FFFu + ((u >> 16) & 1u);
    return (unsigned short)(u >> 16);
}
__device__ __forceinline__ float fbf(unsigned short h) {
    unsigned u = ((unsigned)h) << 16; return __builtin_bit_cast(float, u);
}
__device__ __forceinline__ unsigned pack2bf(float a, float b) {
    return (unsigned)bf16r(a) | ((unsigned)bf16r(b) << 16);
}
__device__ __forceinline__ f32x4 zero4() { f32x4 z; z[0]=0.f; z[1]=0.f; z[2]=0.f; z[3]=0.f; return z; }

// ---------------- K0: per-chunk inclusive cumulative log-decays ----------------
__global__ void k0_logs(const float* __restrict__ beta,
                        const float* __restrict__ bb1, const float* __restrict__ bb2,
                        float* __restrict__ lg1, float* __restrict__ lg2) {
    int blk = blockIdx.x;
    int b = blk / NC_, c = blk % NC_;
    int t = threadIdx.x;            // 0..127
    __shared__ float s1[L_], s2[L_];
    float b1b = clampf(1.f / (1.f + expf(-bb1[0])), 0.01f, 0.995f);
    float b2b = clampf(1.f / (1.f + expf(-bb2[0])), 0.01f, 0.995f);
    float be = clampf(beta[b * T_ + c * L_ + t], 0.01f, 0.995f);
    float x1 = logf(clampf(b1b * be, 0.01f, 0.995f));
    float x2 = logf(clampf(b2b * be, 0.01f, 0.995f));
    s1[t] = x1; s2[t] = x2;
    __syncthreads();
    for (int off = 1; off < L_; off <<= 1) {
        float a1 = (t >= off) ? s1[t - off] : 0.f;
        float a2 = (t >= off) ? s2[t - off] : 0.f;
        __syncthreads();
        s1[t] += a1; s2[t] += a2;
        __syncthreads();
    }
    lg1[b * T_ + c * L_ + t] = s1[t];
    lg2[b * T_ + c * L_ + t] = s2[t];
}

// ---------------- K1: per-chunk state contribution, MFMA, output TRANSPOSED bf16 ----------------
__global__ __launch_bounds__(256) void k1_mfma(
        const float* __restrict__ kk, const float* __restrict__ vv,
        const float* __restrict__ mask,
        const float* __restrict__ lg1, const float* __restrict__ lg2,
        unsigned short* __restrict__ Cws) {
    int ch = blockIdx.x;
    int b = ch / NC_, c = ch % NC_;
    int tbase = b * T_ + c * L_;
    int tid = threadIdx.x, lane = tid & 63, w = tid >> 6;

    __shared__ unsigned short sV[128 * LDK];   // Vt[e][s]
    __shared__ unsigned short sK[128 * LDK];   // (w*phiK*m)^T [d][s]
    __shared__ float wL[2][L_];

    if (tid < 128) {
        float tot1 = lg1[tbase + L_ - 1], tot2 = lg2[tbase + L_ - 1];
        wL[0][tid] = expf(tot1 - lg1[tbase + tid]);
        wL[1][tid] = expf(tot2 - lg2[tbase + tid]);
    }
#pragma unroll
    for (int p = 0; p < 16; ++p) {
        int i = tid + p * 256;
        int s = i & 127, e4 = i >> 7;
        float4 vq = *(const float4*)&vv[(size_t)(tbase + s) * D_ + e4 * 4];
        sV[(e4 * 4 + 0) * LDK + s] = bf16r(vq.x);
        sV[(e4 * 4 + 1) * LDK + s] = bf16r(vq.y);
        sV[(e4 * 4 + 2) * LDK + s] = bf16r(vq.z);
        sV[(e4 * 4 + 3) * LDK + s] = bf16r(vq.w);
    }
    __syncthreads();

    for (int st = 0; st < 2; ++st) {
#pragma unroll
        for (int p = 0; p < 16; ++p) {
            int i = tid + p * 256;
            int s = i & 127, d4 = i >> 7;
            float4 kq = *(const float4*)&kk[(size_t)(tbase + s) * D_ + d4 * 4];
            float m = mask[tbase + s] * wL[st][s];
            float4 pk = phi4(kq);
            sK[(d4 * 4 + 0) * LDK + s] = bf16r(pk.x * m);
            sK[(d4 * 4 + 1) * LDK + s] = bf16r(pk.y * m);
            sK[(d4 * 4 + 2) * LDK + s] = bf16r(pk.z * m);
            sK[(d4 * 4 + 3) * LDK + s] = bf16r(pk.w * m);
        }
        __syncthreads();

        f32x4 acc[2][8];
#pragma unroll
        for (int m = 0; m < 2; ++m)
#pragma unroll
            for (int n = 0; n < 8; ++n) acc[m][n] = zero4();
#pragma unroll
        for (int ks = 0; ks < 4; ++ks) {
            int koff = ks * 32 + (lane >> 4) * 8;
            bf16x8 a0 = *(const bf16x8*)&sV[(w * 32 + (lane & 15)) * LDK + koff];
            bf16x8 a1 = *(const bf16x8*)&sV[(w * 32 + 16 + (lane & 15)) * LDK + koff];
#pragma unroll
            for (int n = 0; n < 8; ++n) {
                bf16x8 bb = *(const bf16x8*)&sK[(n * 16 + (lane & 15)) * LDK + koff];
                acc[0][n] = __builtin_amdgcn_mfma_f32_16x16x32_bf16(a0, bb, acc[0][n], 0, 0, 0);
                acc[1][n] = __builtin_amdgcn_mfma_f32_16x16x32_bf16(a1, bb, acc[1][n], 0, 0, 0);
            }
        }
        unsigned short* Cp = Cws + ((size_t)(st * B_ + b) * NC_ + c) * (D_ * D_);
#pragma unroll
        for (int m = 0; m < 2; ++m)
#pragma unroll
            for (int n = 0; n < 8; ++n)
#pragma unroll
                for (int r = 0; r < 4; ++r) {
                    int e = w * 32 + m * 16 + (lane >> 4) * 4 + r;
                    int d = n * 16 + (lane & 15);
                    Cp[e * D_ + d] = bf16r(acc[m][n][r]);
                }
        __syncthreads();
    }
}

// ---------------- K1z: per-chunk z contribution (fp32, small) ----------------
__global__ void k1z(const float* __restrict__ kk, const float* __restrict__ mask,
                    const float* __restrict__ lg1, const float* __restrict__ lg2,
                    float* __restrict__ zc) {
    int ch = blockIdx.x, st = blockIdx.y;
    int b = ch / NC_, c = ch % NC_;
    const float* lg = st ? lg2 : lg1;
    int tbase = b * T_ + c * L_;
    __shared__ float wL[L_];
    int d = threadIdx.x;
    {
        float tot = lg[tbase + L_ - 1];
        wL[d] = expf(tot - lg[tbase + d]);
    }
    __syncthreads();
    float acc = 0.f;
    for (int s = 0; s < L_; s++) {
        float x = kk[(size_t)(tbase + s) * D_ + d];
        acc += wL[s] * phi_f(x) * mask[tbase + s];
    }
    zc[((size_t)(st * B_ + b) * NC_ + c) * D_ + d] = acc;
}

// ---------------- K2: chunk-state scan over Ct (bf16 storage, fp32 accum) ----------------
__global__ void k2_scan(unsigned short* __restrict__ Cws,
                        const float* __restrict__ lg1, const float* __restrict__ lg2) {
    size_t g = (size_t)blockIdx.x * blockDim.x + threadIdx.x;   // 2*B*D*D = 524288
    int st = (int)(g >> 18);
    int b = (int)((g >> 14) & 15);
    int de = (int)(g & 16383);
    const float* lg = st ? lg2 : lg1;
    size_t base = ((size_t)(st * B_ + b) * NC_) * (D_ * D_) + de;
    float run = 0.f;
    for (int c = 0; c < NC_; c++) {
        float a = expf(lg[b * T_ + c * L_ + L_ - 1]);
        float tmp = fbf(Cws[base + (size_t)c * (D_ * D_)]);
        Cws[base + (size_t)c * (D_ * D_)] = bf16r(run);
        run = a * run + tmp;
    }
}

__global__ void k2z_scan(float* __restrict__ zc,
                         const float* __restrict__ lg1, const float* __restrict__ lg2) {
    int g = blockIdx.x * blockDim.x + threadIdx.x;   // 2*B*D
    int st = g / (B_ * D_);
    int rem = g % (B_ * D_);
    int b = rem / D_;
    int d = rem % D_;
    const float* lg = st ? lg2 : lg1;
    size_t base = ((size_t)(st * B_ + b) * NC_) * D_ + d;
    float run = 0.f;
    for (int c = 0; c < NC_; c++) {
        float a = expf(lg[b * T_ + c * L_ + L_ - 1]);
        float tmp = zc[base + (size_t)c * D_];
        zc[base + (size_t)c * D_] = run;
        run = a * run + tmp;
    }
}

// ---------------- K3 v2: swapped-operand formulation, 3 barriers, per-lane t ----------------
// Each wave owns t-tile w: lane's row t = rbase + w*16 + (lane&15) for ALL phases.
template<int HH>
__device__ __forceinline__ void k3_body(
        int ch,
        const float* __restrict__ qq, const float* __restrict__ kk, const float* __restrict__ vv,
        const float* __restrict__ mask,
        const float* __restrict__ lg1, const float* __restrict__ lg2,
        const unsigned short* __restrict__ Cws, const float* __restrict__ zc,
        float* __restrict__ out,
        unsigned short* bufB, unsigned short* bufP, float* sLg1, float* sLg2) {
    constexpr int SR = HH ? 128 : 64;   // causal s-range
    constexpr int NS = SR / 16;         // S^T row tiles
    constexpr int KS = SR / 32;         // PV k-steps
    constexpr int rbase = HH ? 64 : 0;
    int b = ch / NC_, c = ch % NC_;
    int tbase = b * T_ + c * L_;
    int tid = threadIdx.x, lane = tid & 63, w = tid >> 6;
    int l15 = lane & 15, lg4 = lane >> 4;
    int trow = rbase + w * 16 + l15;    // this lane's t within chunk
    size_t gt = (size_t)(tbase + trow);

    // per-lane scalars (global, coalesced across l15)
    float lg1t = lg1[gt], lg2t = lg2[gt];
    float mt = mask[gt];

    // stage decay logs for P phase
    if (tid < 128) { sLg1[tid] = lg1[tbase + tid]; sLg2[tid] = lg2[tbase + tid]; }

    // ---- phiQ fragments in registers (B-operand layout: col=t, k=d) ----
    bf16x8 qf[4];
    float qr[4][8];
#pragma unroll
    for (int ks = 0; ks < 4; ++ks) {
        const float* qp = &qq[gt * D_ + ks * 32 + lg4 * 8];
        float4 x0 = *(const float4*)qp;
        float4 x1 = *(const float4*)(qp + 4);
        float pq[8] = {phi_f(x0.x), phi_f(x0.y), phi_f(x0.z), phi_f(x0.w),
                       phi_f(x1.x), phi_f(x1.y), phi_f(x1.z), phi_f(x1.w)};
#pragma unroll
        for (int j = 0; j < 8; ++j) {
            unsigned short u = bf16r(pq[j]);
            qf[ks][j] = (short)u;
            qr[ks][j] = fbf(u);
        }
    }

    // ---- stage phiK*m (rows s<SR) into bufB ----
#pragma unroll
    for (int p = 0; p < SR / 8; ++p) {
        int i = tid + p * 256;
        int s = i >> 5, d4 = i & 31;
        float4 kv = *(const float4*)&kk[(size_t)(tbase + s) * D_ + d4 * 4];
        float m = mask[tbase + s];
        uint2 dd;
        dd.x = pack2bf(phi_f(kv.x) * m, phi_f(kv.y) * m);
        dd.y = pack2bf(phi_f(kv.z) * m, phi_f(kv.w) * m);
        *(uint2*)&bufB[s * LDK + d4 * 4] = dd;
    }

    // ---- den inter-chunk part: per-lane dot phiQ . Z ----
    const float* z1p = &zc[((size_t)(0 * B_ + b) * NC_ + c) * D_];
    const float* z2p = &zc[((size_t)(1 * B_ + b) * NC_ + c) * D_];
    float d1 = 0.f, d2 = 0.f;
#pragma unroll
    for (int ks = 0; ks < 4; ++ks) {
        int off = ks * 32 + lg4 * 8;
        float4 za = *(const float4*)(z1p + off), zb = *(const float4*)(z1p + off + 4);
        float4 zca = *(const float4*)(z2p + off), zcb = *(const float4*)(z2p + off + 4);
        d1 += qr[ks][0]*za.x + qr[ks][1]*za.y + qr[ks][2]*za.z + qr[ks][3]*za.w
            + qr[ks][4]*zb.x + qr[ks][5]*zb.y + qr[ks][6]*zb.z + qr[ks][7]*zb.w;
        d2 += qr[ks][0]*zca.x + qr[ks][1]*zca.y + qr[ks][2]*zca.z + qr[ks][3]*zca.w
            + qr[ks][4]*zcb.x + qr[ks][5]*zcb.y + qr[ks][6]*zcb.z + qr[ks][7]*zcb.w;
    }
    d1 += __shfl_xor(d1, 16); d1 += __shfl_xor(d1, 32);
    d2 += __shfl_xor(d2, 16); d2 += __shfl_xor(d2, 32);
    float a1t = expf(lg1t), a2t = expf(lg2t);
    float den_z = a1t * d1 + a2t * d2;

    // ---- QH: acc_o^T[e][t] += (a_st * phiQ) . H_st, A-frags direct from global ----
    f32x4 acc_o[8];
#pragma unroll
    for (int m = 0; m < 8; ++m) acc_o[m] = zero4();
#pragma unroll
    for (int st = 0; st < 2; ++st) {
        const unsigned short* Hp = Cws + ((size_t)(st * B_ + b) * NC_ + c) * (D_ * D_);
        float sc = st ? a2t : a1t;
#pragma unroll
        for (int ks = 0; ks < 4; ++ks) {
            bf16x8 qs;
#pragma unroll
            for (int j = 0; j < 8; ++j)
                qs[j] = (short)bf16r(fbf((unsigned short)qf[ks][j]) * sc);
            int koff = ks * 32 + lg4 * 8;
#pragma unroll
            for (int m = 0; m < 8; ++m) {
                bf16x8 hf = *(const bf16x8*)&Hp[(size_t)(m * 16 + l15) * D_ + koff];
                acc_o[m] = __builtin_amdgcn_mfma_f32_16x16x32_bf16(hf, qs, acc_o[m], 0, 0, 0);
            }
        }
    }

    __syncthreads();   // B1: sLg + phiK visible

    // ---- S^T = phiK @ phiQ^T ----
    f32x4 accs[NS];
#pragma unroll
    for (int m = 0; m < NS; ++m) accs[m] = zero4();
#pragma unroll
    for (int ks = 0; ks < 4; ++ks) {
        int koff = ks * 32 + lg4 * 8;
#pragma unroll
        for (int m = 0; m < NS; ++m) {
            bf16x8 kf = *(const bf16x8*)&bufB[(m * 16 + l15) * LDK + koff];
            accs[m] = __builtin_amdgcn_mfma_f32_16x16x32_bf16(kf, qf[ks], accs[m], 0, 0, 0);
        }
    }

    // ---- P^T: decay+mask, rowsum, pack -> bufP[t][s] ----
    float rs = 0.f;
#pragma unroll
    for (int m = 0; m < NS; ++m) {
        int s0 = m * 16 + lg4 * 4;
        float4 l1s = *(const float4*)&sLg1[s0];
        float4 l2s = *(const float4*)&sLg2[s0];
        float l1a[4] = {l1s.x, l1s.y, l1s.z, l1s.w};
        float l2a[4] = {l2s.x, l2s.y, l2s.z, l2s.w};
        float pv[4];
#pragma unroll
        for (int r = 0; r < 4; ++r) {
            int s = s0 + r;
            float p = 0.f;
            if (s <= trow)
                p = accs[m][r] * (expf(lg1t - l1a[r]) + expf(lg2t - l2a[r]));
            pv[r] = p; rs += p;
        }
        uint2 dd;
        dd.x = pack2bf(pv[0], pv[1]);
        dd.y = pack2bf(pv[2], pv[3]);
        *(uint2*)&bufP[(w * 16 + l15) * LDK + s0] = dd;
    }
    rs += __shfl_xor(rs, 16); rs += __shfl_xor(rs, 32);
    float osc = mt / fmaxf(den_z + rs, 1e-6f);

    __syncthreads();   // B2: S^T reads of bufB complete

    // ---- stage Vt[e][s] into bufB ----
#pragma unroll
    for (int p = 0; p < SR / 8; ++p) {
        int i = tid + p * 256;
        int s = i & (SR - 1), e4 = i / SR;
        float4 vq = *(const float4*)&vv[(size_t)(tbase + s) * D_ + e4 * 4];
        bufB[(e4 * 4 + 0) * LDK + s] = bf16r(vq.x);
        bufB[(e4 * 4 + 1) * LDK + s] = bf16r(vq.y);
        bufB[(e4 * 4 + 2) * LDK + s] = bf16r(vq.z);
        bufB[(e4 * 4 + 3) * LDK + s] = bf16r(vq.w);
    }
    __syncthreads();   // B3

    // ---- O^T += Vt @ P^T ----
#pragma unroll
    for (int ks = 0; ks < KS; ++ks) {
        int koff = ks * 32 + lg4 * 8;
        bf16x8 pf = *(const bf16x8*)&bufP[(w * 16 + l15) * LDK + koff];
#pragma unroll
        for (int m = 0; m < 8; ++m) {
            bf16x8 vf = *(const bf16x8*)&bufB[(m * 16 + l15) * LDK + koff];
            acc_o[m] = __builtin_amdgcn_mfma_f32_16x16x32_bf16(vf, pf, acc_o[m], 0, 0, 0);
        }
    }

    // ---- store: row t = per-lane, col e = m*16+lg4*4+r ----
#pragma unroll
    for (int m = 0; m < 8; ++m)
#pragma unroll
        for (int r = 0; r < 4; ++r)
            out[gt * D_ + m * 16 + lg4 * 4 + r] = acc_o[m][r] * osc;
}

__global__ __launch_bounds__(256, 3) void k3_v2(
        const float* __restrict__ qq, const float* __restrict__ kk, const float* __restrict__ vv,
        const float* __restrict__ mask,
        const float* __restrict__ lg1, const float* __restrict__ lg2,
        const unsigned short* __restrict__ Cws, const float* __restrict__ zc,
        float* __restrict__ out) {
    __shared__ unsigned short bufB[128 * LDK];   // 34816 B
    __shared__ unsigned short bufP[64 * LDK];    // 17408 B
    __shared__ float sLg1[L_], sLg2[L_];         // 1024 B   => 53248 B total, 3 blocks/CU
    int g = blockIdx.x;
    int ch = ((g >> 4) << 3) | (g & 7);          // XCD pairing: (ch,HH0) and (ch,HH1) same XCD
    if ((g >> 3) & 1)
        k3_body<1>(ch, qq, kk, vv, mask, lg1, lg2, Cws, zc, out, bufB, bufP, sLg1, sLg2);
    else
        k3_body<0>(ch, qq, kk, vv, mask, lg1, lg2, Cws, zc, out, bufB, bufP, sLg1, sLg2);
}

extern "C" void kernel_launch(void* const* d_in, const int* in_sizes, int n_in,
                              void* d_out, int out_size, void* d_ws, size_t ws_size,
                              hipStream_t stream) {
    const float* q    = (const float*)d_in[0];
    const float* k    = (const float*)d_in[1];
    const float* v    = (const float*)d_in[2];
    const float* beta = (const float*)d_in[3];
    const float* mask = (const float*)d_in[4];
    const float* bb1  = (const float*)d_in[5];
    const float* bb2  = (const float*)d_in[6];
    float* out = (float*)d_out;

    size_t n_lg = (size_t)B_ * T_;                       // 65536
    size_t n_z  = (size_t)2 * B_ * NC_ * D_;             // 131072
    size_t n_C  = (size_t)2 * B_ * NC_ * D_ * D_;        // 16777216 bf16 elems
    size_t need = (2 * n_lg + n_z) * sizeof(float) + n_C * sizeof(unsigned short);
    if (ws_size < need) return;

    float* lg1 = (float*)d_ws;
    float* lg2 = lg1 + n_lg;
    float* zc  = lg2 + n_lg;
    unsigned short* Cws = (unsigned short*)(zc + n_z);

    k0_logs<<<CH_, L_, 0, stream>>>(beta, bb1, bb2, lg1, lg2);
    k1_mfma<<<CH_, 256, 0, stream>>>(k, v, mask, lg1, lg2, Cws);
    k1z<<<dim3(CH_, 2), L_, 0, stream>>>(k, mask, lg1, lg2, zc);
    k2_scan<<<(2 * B_ * D_ * D_) / 256, 256, 0, stream>>>(Cws, lg1, lg2);
    k2z_scan<<<(2 * B_ * D_) / 256, 256, 0, stream>>>(zc, lg1, lg2);
    k3_v2<<<2 * CH_, 256, 0, stream>>>(q, k, v, mask, lg1, lg2, Cws, zc, out);
}

// Round 4
// 143.488 us; speedup vs baseline: 1.0462x; 1.0462x over previous
//
#include <hip/hip_runtime.h>

#define B_ 16
#define T_ 4096
#define D_ 128
#define L_ 128
#define NC_ 32            // T_/L_
#define CH_ (B_*NC_)      // 512 chunks
#define LDK 136           // padded bf16 row stride for k1 LDS
#define LDP 136           // padded stride for k3 wave-private P buffer

typedef __attribute__((ext_vector_type(8))) short bf16x8;
typedef __attribute__((ext_vector_type(4))) float f32x4;

__device__ __forceinline__ float clampf(float x, float lo, float hi) {
    return fminf(fmaxf(x, lo), hi);
}
__device__ __forceinline__ float phi_f(float x) {   // elu(x)+1
    return x > 0.f ? x + 1.f : expf(x);
}
__device__ __forceinline__ unsigned short bf16r(float f) {  // RNE f32->bf16
    unsigned u = __builtin_bit_cast(unsigned, f);
    u += 0x7FFFu + ((u >> 16) & 1u);
    return (unsigned short)(u >> 16);
}
__device__ __forceinline__ float fbf(unsigned short h) {
    unsigned u = ((unsigned)h) << 16; return __builtin_bit_cast(float, u);
}
__device__ __forceinline__ unsigned pack2bf(float a, float b) {
    return (unsigned)bf16r(a) | ((unsigned)bf16r(b) << 16);
}
__device__ __forceinline__ uint4 pack8(const float* f) {
    uint4 r;
    r.x = pack2bf(f[0], f[1]); r.y = pack2bf(f[2], f[3]);
    r.z = pack2bf(f[4], f[5]); r.w = pack2bf(f[6], f[7]);
    return r;
}
__device__ __forceinline__ f32x4 zero4() { f32x4 z; z[0]=0.f; z[1]=0.f; z[2]=0.f; z[3]=0.f; return z; }

// Fragment-tiled index for a 128(row) x 128(k) bf16 matrix, 16x16x32 MFMA A-operand:
//   tile(m,ks), lane(lg4*16+l15), j:  elem[row=m*16+l15][k=ks*32+lg4*8+j]
//   flat = ((m*4+ks)*64 + lane)*8 + j       (16 KB per matrix)

// ---------------- K0: per-chunk inclusive cumulative log-decays ----------------
__global__ void k0_logs(const float* __restrict__ beta,
                        const float* __restrict__ bb1, const float* __restrict__ bb2,
                        float* __restrict__ lg1, float* __restrict__ lg2) {
    int blk = blockIdx.x;
    int b = blk / NC_, c = blk % NC_;
    int t = threadIdx.x;            // 0..127
    __shared__ float s1[L_], s2[L_];
    float b1b = clampf(1.f / (1.f + expf(-bb1[0])), 0.01f, 0.995f);
    float b2b = clampf(1.f / (1.f + expf(-bb2[0])), 0.01f, 0.995f);
    float be = clampf(beta[b * T_ + c * L_ + t], 0.01f, 0.995f);
    float x1 = logf(clampf(b1b * be, 0.01f, 0.995f));
    float x2 = logf(clampf(b2b * be, 0.01f, 0.995f));
    s1[t] = x1; s2[t] = x2;
    __syncthreads();
    for (int off = 1; off < L_; off <<= 1) {
        float a1 = (t >= off) ? s1[t - off] : 0.f;
        float a2 = (t >= off) ? s2[t - off] : 0.f;
        __syncthreads();
        s1[t] += a1; s2[t] += a2;
        __syncthreads();
    }
    lg1[b * T_ + c * L_ + t] = s1[t];
    lg2[b * T_ + c * L_ + t] = s2[t];
}

// ---------------- K_pre: frag-tiled bf16 phiK*m and V^T per chunk ----------------
__global__ __launch_bounds__(256) void k_pre(
        const float* __restrict__ kk, const float* __restrict__ vv,
        const float* __restrict__ mask,
        unsigned short* __restrict__ phiKT, unsigned short* __restrict__ VtT) {
    int ch = blockIdx.x;
    int b = ch / NC_, c = ch % NC_;
    int tbase = b * T_ + c * L_;
    int tid = threadIdx.x;
    size_t cb = (size_t)ch * (D_ * L_);   // 16384 elems per chunk matrix
    __shared__ unsigned short sV[32 * 136];

    // phiK*m tiled: thread holds (row s, 8 consecutive k=d) -> exactly one frag octet
#pragma unroll
    for (int p = 0; p < 8; ++p) {
        int i = tid + p * 256;          // 2048 = 128 s x 16 dgrp
        int s = i >> 4, dg = i & 15, d0 = dg * 8;
        const float* kp = &kk[(size_t)(tbase + s) * D_ + d0];
        float4 x0 = *(const float4*)kp;
        float4 x1 = *(const float4*)(kp + 4);
        float m = mask[tbase + s];
        float pq[8] = {phi_f(x0.x)*m, phi_f(x0.y)*m, phi_f(x0.z)*m, phi_f(x0.w)*m,
                       phi_f(x1.x)*m, phi_f(x1.y)*m, phi_f(x1.z)*m, phi_f(x1.w)*m};
        int mt = s >> 4, ks = d0 >> 5, lg4 = (d0 >> 3) & 3, l15 = s & 15;
        *(uint4*)&phiKT[cb + (size_t)(((mt * 4 + ks) * 64 + lg4 * 16 + l15) * 8)] = pack8(pq);
    }

    // V^T tiled: rows = e, k = s. j-dim runs along s -> transpose via LDS slabs of 32 s.
    for (int slab = 0; slab < 4; ++slab) {
        __syncthreads();    // protect sV from previous slab's readers
#pragma unroll
        for (int p = 0; p < 2; ++p) {
            int i = tid + p * 256;      // 512 = 32 s x 16 egrp
            int sp = i >> 4, eg = i & 15, e0 = eg * 8;
            const float* vp = &vv[(size_t)(tbase + slab * 32 + sp) * D_ + e0];
            float4 x0 = *(const float4*)vp;
            float4 x1 = *(const float4*)(vp + 4);
            float pv8[8] = {x0.x, x0.y, x0.z, x0.w, x1.x, x1.y, x1.z, x1.w};
            *(uint4*)&sV[sp * 136 + e0] = pack8(pv8);
        }
        __syncthreads();
#pragma unroll
        for (int p = 0; p < 2; ++p) {
            int i = tid + p * 256;      // 512 = 8 mg x 64 lane
            int mg = i >> 6, ln = i & 63;
            int lg4 = ln >> 4, l15 = ln & 15;
            unsigned short u[8];
#pragma unroll
            for (int j = 0; j < 8; ++j)
                u[j] = sV[(lg4 * 8 + j) * 136 + mg * 16 + l15];
            uint4 r;
            r.x = (unsigned)u[0] | ((unsigned)u[1] << 16);
            r.y = (unsigned)u[2] | ((unsigned)u[3] << 16);
            r.z = (unsigned)u[4] | ((unsigned)u[5] << 16);
            r.w = (unsigned)u[6] | ((unsigned)u[7] << 16);
            *(uint4*)&VtT[cb + (size_t)(((mg * 4 + slab) * 64 + ln) * 8)] = r;
        }
    }
}

// ---------------- K1: chunk state contribution, A-frags from VtT, tiled bf16 out ----------------
__global__ __launch_bounds__(256) void k1_v4(
        const float* __restrict__ kk, const float* __restrict__ mask,
        const float* __restrict__ lg1, const float* __restrict__ lg2,
        const unsigned short* __restrict__ VtT,
        unsigned short* __restrict__ Cws) {
    int ch = blockIdx.x;
    int b = ch / NC_, c = ch % NC_;
    int tbase = b * T_ + c * L_;
    int tid = threadIdx.x, lane = tid & 63, w = tid >> 6;
    int l15 = lane & 15, lg4 = lane >> 4;

    __shared__ unsigned short sK[128 * LDK];   // (w*phiK*m)^T [d][s]
    __shared__ float wL[2][L_];

    if (tid < 128) {
        float tot1 = lg1[tbase + L_ - 1], tot2 = lg2[tbase + L_ - 1];
        wL[0][tid] = expf(tot1 - lg1[tbase + tid]);
        wL[1][tid] = expf(tot2 - lg2[tbase + tid]);
    }
    __syncthreads();

    const unsigned short* Vch = VtT + (size_t)ch * 16384;

    for (int st = 0; st < 2; ++st) {
#pragma unroll
        for (int p = 0; p < 16; ++p) {
            int i = tid + p * 256;
            int s = i & 127, d4 = i >> 7;
            float4 kq = *(const float4*)&kk[(size_t)(tbase + s) * D_ + d4 * 4];
            float m = mask[tbase + s] * wL[st][s];
            sK[(d4 * 4 + 0) * LDK + s] = bf16r(phi_f(kq.x) * m);
            sK[(d4 * 4 + 1) * LDK + s] = bf16r(phi_f(kq.y) * m);
            sK[(d4 * 4 + 2) * LDK + s] = bf16r(phi_f(kq.z) * m);
            sK[(d4 * 4 + 3) * LDK + s] = bf16r(phi_f(kq.w) * m);
        }
        __syncthreads();

        f32x4 acc[2][8];
#pragma unroll
        for (int m = 0; m < 2; ++m)
#pragma unroll
            for (int n = 0; n < 8; ++n) acc[m][n] = zero4();
#pragma unroll
        for (int ks = 0; ks < 4; ++ks) {
            int koff = ks * 32 + lg4 * 8;
            bf16x8 a0 = *(const bf16x8*)&Vch[(size_t)((((w * 2 + 0) * 4 + ks) * 64 + lane) * 8)];
            bf16x8 a1 = *(const bf16x8*)&Vch[(size_t)((((w * 2 + 1) * 4 + ks) * 64 + lane) * 8)];
#pragma unroll
            for (int n = 0; n < 8; ++n) {
                bf16x8 bb = *(const bf16x8*)&sK[(n * 16 + l15) * LDK + koff];
                acc[0][n] = __builtin_amdgcn_mfma_f32_16x16x32_bf16(a0, bb, acc[0][n], 0, 0, 0);
                acc[1][n] = __builtin_amdgcn_mfma_f32_16x16x32_bf16(a1, bb, acc[1][n], 0, 0, 0);
            }
        }
        unsigned short* Cp = Cws + ((size_t)(st * B_ + b) * NC_ + c) * (D_ * D_);
#pragma unroll
        for (int m = 0; m < 2; ++m)
#pragma unroll
            for (int n = 0; n < 8; ++n)
#pragma unroll
                for (int r = 0; r < 4; ++r) {
                    int e = w * 32 + m * 16 + lg4 * 4 + r;   // row of Ct
                    int d = n * 16 + l15;                    // k-dim
                    int tm = e >> 4, tl = e & 15, tk = d >> 5, tg = (d >> 3) & 3, tj = d & 7;
                    Cp[(size_t)(((tm * 4 + tk) * 64 + tg * 16 + tl) * 8 + tj)] = bf16r(acc[m][n][r]);
                }
        __syncthreads();
    }
}

// ---------------- K1z: per-chunk z contribution ----------------
__global__ void k1z(const float* __restrict__ kk, const float* __restrict__ mask,
                    const float* __restrict__ lg1, const float* __restrict__ lg2,
                    float* __restrict__ zc) {
    int ch = blockIdx.x, st = blockIdx.y;
    int b = ch / NC_, c = ch % NC_;
    const float* lg = st ? lg2 : lg1;
    int tbase = b * T_ + c * L_;
    __shared__ float wL[L_];
    int d = threadIdx.x;
    {
        float tot = lg[tbase + L_ - 1];
        wL[d] = expf(tot - lg[tbase + d]);
    }
    __syncthreads();
    float acc = 0.f;
    for (int s = 0; s < L_; s++) {
        float x = kk[(size_t)(tbase + s) * D_ + d];
        acc += wL[s] * phi_f(x) * mask[tbase + s];
    }
    zc[((size_t)(st * B_ + b) * NC_ + c) * D_ + d] = acc;
}

// ---------------- K2: chunk-state scan (tiled layout is elementwise-transparent) ----------------
__global__ void k2_scan(unsigned short* __restrict__ Cws,
                        const float* __restrict__ lg1, const float* __restrict__ lg2) {
    size_t g = (size_t)blockIdx.x * blockDim.x + threadIdx.x;   // 2*B*D*D = 524288
    int st = (int)(g >> 18);
    int b = (int)((g >> 14) & 15);
    int de = (int)(g & 16383);
    const float* lg = st ? lg2 : lg1;
    size_t base = ((size_t)(st * B_ + b) * NC_) * (D_ * D_) + de;
    float run = 0.f;
    for (int c = 0; c < NC_; c++) {
        float a = expf(lg[b * T_ + c * L_ + L_ - 1]);
        float tmp = fbf(Cws[base + (size_t)c * (D_ * D_)]);
        Cws[base + (size_t)c * (D_ * D_)] = bf16r(run);
        run = a * run + tmp;
    }
}

__global__ void k2z_scan(float* __restrict__ zc,
                         const float* __restrict__ lg1, const float* __restrict__ lg2) {
    int g = blockIdx.x * blockDim.x + threadIdx.x;   // 2*B*D
    int st = g / (B_ * D_);
    int rem = g % (B_ * D_);
    int b = rem / D_;
    int d = rem % D_;
    const float* lg = st ? lg2 : lg1;
    size_t base = ((size_t)(st * B_ + b) * NC_) * D_ + d;
    float run = 0.f;
    for (int c = 0; c < NC_; c++) {
        float a = expf(lg[b * T_ + c * L_ + L_ - 1]);
        float tmp = zc[base + (size_t)c * D_];
        zc[base + (size_t)c * D_] = run;
        run = a * run + tmp;
    }
}

// ---------------- K3 v4: zero-barrier, all operands frag-tiled ----------------
template<int HH>
__device__ __forceinline__ void k3_body(
        int ch,
        const float* __restrict__ qq, const float* __restrict__ mask,
        const float* __restrict__ lg1, const float* __restrict__ lg2,
        const unsigned short* __restrict__ phiKT, const unsigned short* __restrict__ VtT,
        const unsigned short* __restrict__ Cws, const float* __restrict__ zc,
        float* __restrict__ out, unsigned short* bufPw) {
    constexpr int SR = HH ? 128 : 64;   // causal s-range
    constexpr int NS = SR / 16;
    constexpr int KS = SR / 32;
    constexpr int rbase = HH * 64;
    int b = ch / NC_, c = ch % NC_;
    int tbase = b * T_ + c * L_;
    int tid = threadIdx.x, lane = tid & 63;
    int w = tid >> 6, l15 = lane & 15, lg4 = lane >> 4;
    int trow = rbase + w * 16 + l15;
    size_t gt = (size_t)(tbase + trow);
    size_t cb = (size_t)ch * 16384;

    float lg1t = lg1[gt], lg2t = lg2[gt], mt = mask[gt];
    float a1t = expf(lg1t), a2t = expf(lg2t);

    // ---- phiQ B-fragments in registers + den inter-chunk dot ----
    const float* z1p = &zc[((size_t)(0 * B_ + b) * NC_ + c) * D_];
    const float* z2p = &zc[((size_t)(1 * B_ + b) * NC_ + c) * D_];
    bf16x8 qf[4];
    float d1 = 0.f, d2 = 0.f;
#pragma unroll
    for (int ks = 0; ks < 4; ++ks) {
        int off = ks * 32 + lg4 * 8;
        const float* qp = &qq[gt * D_ + off];
        float4 x0 = *(const float4*)qp;
        float4 x1 = *(const float4*)(qp + 4);
        float pq[8] = {phi_f(x0.x), phi_f(x0.y), phi_f(x0.z), phi_f(x0.w),
                       phi_f(x1.x), phi_f(x1.y), phi_f(x1.z), phi_f(x1.w)};
        float4 za = *(const float4*)(z1p + off), zb = *(const float4*)(z1p + off + 4);
        float4 zc2 = *(const float4*)(z2p + off), zd = *(const float4*)(z2p + off + 4);
        float z1a[8] = {za.x, za.y, za.z, za.w, zb.x, zb.y, zb.z, zb.w};
        float z2a[8] = {zc2.x, zc2.y, zc2.z, zc2.w, zd.x, zd.y, zd.z, zd.w};
#pragma unroll
        for (int j = 0; j < 8; ++j) {
            unsigned short u = bf16r(pq[j]);
            qf[ks][j] = (short)u;
            float fq = fbf(u);
            d1 += fq * z1a[j];
            d2 += fq * z2a[j];
        }
    }
    d1 += __shfl_xor(d1, 16); d1 += __shfl_xor(d1, 32);
    d2 += __shfl_xor(d2, 16); d2 += __shfl_xor(d2, 32);
    float den_z = a1t * d1 + a2t * d2;

    // ---- S^T = phiK @ phiQ^T (A-frags coalesced from phiKT), then P -> bufP ----
    float rs = 0.f;
#pragma unroll
    for (int mh = 0; mh < NS / 4; ++mh) {
        f32x4 accs[4];
#pragma unroll
        for (int m = 0; m < 4; ++m) accs[m] = zero4();
#pragma unroll
        for (int ks = 0; ks < 4; ++ks) {
#pragma unroll
            for (int m = 0; m < 4; ++m) {
                int sm = mh * 4 + m;
                bf16x8 kf = *(const bf16x8*)&phiKT[cb + (size_t)(((sm * 4 + ks) * 64 + lane) * 8)];
                accs[m] = __builtin_amdgcn_mfma_f32_16x16x32_bf16(kf, qf[ks], accs[m], 0, 0, 0);
            }
        }
#pragma unroll
        for (int m = 0; m < 4; ++m) {
            int sm = mh * 4 + m;
            int s0 = sm * 16 + lg4 * 4;
            float4 l1s = *(const float4*)&lg1[tbase + s0];
            float4 l2s = *(const float4*)&lg2[tbase + s0];
            float l1a[4] = {l1s.x, l1s.y, l1s.z, l1s.w};
            float l2a[4] = {l2s.x, l2s.y, l2s.z, l2s.w};
            float pv[4];
#pragma unroll
            for (int r = 0; r < 4; ++r) {
                int s = s0 + r;
                float p = 0.f;
                if (s <= trow)
                    p = accs[m][r] * (expf(lg1t - l1a[r]) + expf(lg2t - l2a[r]));
                pv[r] = p; rs += p;
            }
            uint2 dd;
            dd.x = pack2bf(pv[0], pv[1]);
            dd.y = pack2bf(pv[2], pv[3]);
            *(uint2*)&bufPw[l15 * LDP + s0] = dd;
        }
    }
    rs += __shfl_xor(rs, 16); rs += __shfl_xor(rs, 32);
    float osc = mt / fmaxf(den_z + rs, 1e-6f);

    // ---- QH: acc_o^T[e][t] += (a_st*phiQ) . H_st  (A-frags coalesced from tiled Cws) ----
    f32x4 acc_o[8];
#pragma unroll
    for (int m = 0; m < 8; ++m) acc_o[m] = zero4();
#pragma unroll
    for (int st = 0; st < 2; ++st) {
        const unsigned short* Hp = Cws + ((size_t)(st * B_ + b) * NC_ + c) * (D_ * D_);
        float sc = st ? a2t : a1t;
#pragma unroll
        for (int ks = 0; ks < 4; ++ks) {
            bf16x8 qs;
#pragma unroll
            for (int j = 0; j < 8; ++j)
                qs[j] = (short)bf16r(fbf((unsigned short)qf[ks][j]) * sc);
#pragma unroll
            for (int m = 0; m < 8; ++m) {
                bf16x8 hf = *(const bf16x8*)&Hp[(size_t)(((m * 4 + ks) * 64 + lane) * 8)];
                acc_o[m] = __builtin_amdgcn_mfma_f32_16x16x32_bf16(hf, qs, acc_o[m], 0, 0, 0);
            }
        }
    }

    // ---- PV: acc_o += Vt @ P^T (A from VtT, B re-read by same wave: no barrier) ----
#pragma unroll
    for (int ks = 0; ks < KS; ++ks) {
        bf16x8 pf = *(const bf16x8*)&bufPw[l15 * LDP + ks * 32 + lg4 * 8];
#pragma unroll
        for (int m = 0; m < 8; ++m) {
            bf16x8 vf = *(const bf16x8*)&VtT[cb + (size_t)(((m * 4 + ks) * 64 + lane) * 8)];
            acc_o[m] = __builtin_amdgcn_mfma_f32_16x16x32_bf16(vf, pf, acc_o[m], 0, 0, 0);
        }
    }

    // ---- store (float4 per m-tile) ----
#pragma unroll
    for (int m = 0; m < 8; ++m) {
        float4 o;
        o.x = acc_o[m][0] * osc; o.y = acc_o[m][1] * osc;
        o.z = acc_o[m][2] * osc; o.w = acc_o[m][3] * osc;
        *(float4*)&out[gt * D_ + m * 16 + lg4 * 4] = o;
    }
}

__global__ __launch_bounds__(256, 5) void k3_v4(
        const float* __restrict__ qq, const float* __restrict__ mask,
        const float* __restrict__ lg1, const float* __restrict__ lg2,
        const unsigned short* __restrict__ phiKT, const unsigned short* __restrict__ VtT,
        const unsigned short* __restrict__ Cws, const float* __restrict__ zc,
        float* __restrict__ out) {
    __shared__ unsigned short bufP[4][16 * LDP];   // wave-private P, 17408 B
    int g = blockIdx.x;
    int ch = (g & 7) | ((g >> 4) << 3);            // XCD pairing of (ch,HH0)/(ch,HH1)
    int w = threadIdx.x >> 6;
    if ((g >> 3) & 1)
        k3_body<1>(ch, qq, mask, lg1, lg2, phiKT, VtT, Cws, zc, out, &bufP[w][0]);
    else
        k3_body<0>(ch, qq, mask, lg1, lg2, phiKT, VtT, Cws, zc, out, &bufP[w][0]);
}

extern "C" void kernel_launch(void* const* d_in, const int* in_sizes, int n_in,
                              void* d_out, int out_size, void* d_ws, size_t ws_size,
                              hipStream_t stream) {
    const float* q    = (const float*)d_in[0];
    const float* k    = (const float*)d_in[1];
    const float* v    = (const float*)d_in[2];
    const float* beta = (const float*)d_in[3];
    const float* mask = (const float*)d_in[4];
    const float* bb1  = (const float*)d_in[5];
    const float* bb2  = (const float*)d_in[6];
    float* out = (float*)d_out;

    size_t n_lg = (size_t)B_ * T_;                       // 65536
    size_t n_z  = (size_t)2 * B_ * NC_ * D_;             // 131072
    size_t n_C  = (size_t)2 * B_ * NC_ * D_ * D_;        // 16777216 bf16
    size_t n_kt = (size_t)B_ * T_ * D_;                  // 8388608 bf16
    size_t need = (2 * n_lg + n_z) * sizeof(float) + (n_C + 2 * n_kt) * sizeof(unsigned short);
    if (ws_size < need) return;

    float* lg1 = (float*)d_ws;
    float* lg2 = lg1 + n_lg;
    float* zc  = lg2 + n_lg;
    unsigned short* Cws   = (unsigned short*)(zc + n_z);
    unsigned short* phiKT = Cws + n_C;
    unsigned short* VtT   = phiKT + n_kt;

    k0_logs<<<CH_, L_, 0, stream>>>(beta, bb1, bb2, lg1, lg2);
    k_pre<<<CH_, 256, 0, stream>>>(k, v, mask, phiKT, VtT);
    k1_v4<<<CH_, 256, 0, stream>>>(k, mask, lg1, lg2, VtT, Cws);
    k1z<<<dim3(CH_, 2), L_, 0, stream>>>(k, mask, lg1, lg2, zc);
    k2_scan<<<(2 * B_ * D_ * D_) / 256, 256, 0, stream>>>(Cws, lg1, lg2);
    k2z_scan<<<(2 * B_ * D_) / 256, 256, 0, stream>>>(zc, lg1, lg2);
    k3_v4<<<2 * CH_, 256, 0, stream>>>(q, mask, lg1, lg2, phiKT, VtT, Cws, zc, out);
}